// Round 1
// baseline (1461.856 us; speedup 1.0000x reference)
//
#include <hip/hip_runtime.h>
#include <math.h>

#define L_SEQ 1024
#define DDIM  256
#define ADIM  128
#define NB    32

// ---------------------------------------------------------------------------
// Kernel 1: generic tiled fp32 GEMM: C[M,N] = A[M,K] @ B[K,N]  (row-major)
// BM=64, BN=64, BK=16, 256 threads (16x16), 4x4 micro-tile.
// ---------------------------------------------------------------------------
__global__ __launch_bounds__(256) void gemm_f32(const float* __restrict__ A,
                                                const float* __restrict__ B,
                                                float* __restrict__ C,
                                                int M, int N, int K) {
    __shared__ float As[64][17];   // pad 17 to spread banks for column reads
    __shared__ float Bs[16][64];
    const int tid = threadIdx.x;
    const int tx = tid & 15;
    const int ty = tid >> 4;
    const int m0 = blockIdx.y * 64;
    const int n0 = blockIdx.x * 64;

    float acc[4][4] = {};
    for (int k0 = 0; k0 < K; k0 += 16) {
        {   // A tile 64x16: each thread one float4
            int row = tid >> 2;
            int kk  = (tid & 3) * 4;
            float4 v = *reinterpret_cast<const float4*>(&A[(size_t)(m0 + row) * K + k0 + kk]);
            As[row][kk + 0] = v.x; As[row][kk + 1] = v.y;
            As[row][kk + 2] = v.z; As[row][kk + 3] = v.w;
        }
        {   // B tile 16x64
            int kk  = tid >> 4;
            int col = (tid & 15) * 4;
            *reinterpret_cast<float4*>(&Bs[kk][col]) =
                *reinterpret_cast<const float4*>(&B[(size_t)(k0 + kk) * N + n0 + col]);
        }
        __syncthreads();
        #pragma unroll
        for (int kk = 0; kk < 16; ++kk) {
            float a[4];
            #pragma unroll
            for (int i = 0; i < 4; ++i) a[i] = As[ty * 4 + i][kk];
            float4 bv = *reinterpret_cast<const float4*>(&Bs[kk][tx * 4]);
            float b[4] = {bv.x, bv.y, bv.z, bv.w};
            #pragma unroll
            for (int i = 0; i < 4; ++i)
                #pragma unroll
                for (int j = 0; j < 4; ++j)
                    acc[i][j] = fmaf(a[i], b[j], acc[i][j]);
        }
        __syncthreads();
    }
    #pragma unroll
    for (int i = 0; i < 4; ++i) {
        float4 v = {acc[i][0], acc[i][1], acc[i][2], acc[i][3]};
        *reinterpret_cast<float4*>(&C[(size_t)(m0 + ty * 4 + i) * N + n0 + tx * 4]) = v;
    }
}

// ---------------------------------------------------------------------------
// Kernel 2/3: fused  logits[b, r] = ( tanh( Bias[b,r,:] + sum_c tanh(Q[b,r,:]
//             . K[b,c,:]) * V[b,c,:] ) ) . w
// Q,K: [B,L,256]  V,Bias: [B,L,128]  w: [128]  logits: [B,L]
// One block per (64-row tile, batch). 256 threads. Key chunks of 32.
// ---------------------------------------------------------------------------
#define QS 260   // LDS stride for 256-wide rows (keeps float4 alignment, spreads banks)

__global__ __launch_bounds__(256) void fused_logits(
        const float* __restrict__ Qg, const float* __restrict__ Kg,
        const float* __restrict__ Vg, const float* __restrict__ Bias,
        const float* __restrict__ w,  float* __restrict__ logits) {
    __shared__ float Qs[64][QS];
    __shared__ float Ks[32][QS];
    __shared__ float Vs[32][ADIM];
    __shared__ float Ss[64][33];
    __shared__ float red[64][16];

    const int tid = threadIdx.x;
    const int tx = tid & 15;
    const int ty = tid >> 4;
    const int b  = blockIdx.y;
    const int r0 = blockIdx.x * 64;

    // stage Q tile (64 x 256), read once, reused for all 32 key chunks
    const size_t qbase = ((size_t)b * L_SEQ + r0) * DDIM;
    #pragma unroll
    for (int it = 0; it < 16; ++it) {
        int idx = it * 1024 + tid * 4;
        int row = idx >> 8, col = idx & 255;
        *reinterpret_cast<float4*>(&Qs[row][col]) =
            *reinterpret_cast<const float4*>(&Qg[qbase + (size_t)row * DDIM + col]);
    }

    float acc[4][8] = {};
    for (int c0 = 0; c0 < L_SEQ; c0 += 32) {
        __syncthreads();   // previous chunk's Ss/Ks/Vs consumers done (also covers Q stage)
        const size_t kbase = ((size_t)b * L_SEQ + c0) * DDIM;
        #pragma unroll
        for (int it = 0; it < 8; ++it) {
            int idx = it * 1024 + tid * 4;
            int row = idx >> 8, col = idx & 255;
            *reinterpret_cast<float4*>(&Ks[row][col]) =
                *reinterpret_cast<const float4*>(&Kg[kbase + (size_t)row * DDIM + col]);
        }
        const size_t vbase = ((size_t)b * L_SEQ + c0) * ADIM;
        #pragma unroll
        for (int it = 0; it < 4; ++it) {
            int idx = it * 1024 + tid * 4;
            int row = idx >> 7, col = idx & 127;
            *reinterpret_cast<float4*>(&Vs[row][col]) =
                *reinterpret_cast<const float4*>(&Vg[vbase + (size_t)row * ADIM + col]);
        }
        __syncthreads();

        // S phase: S[64][32] = Qs @ Ks^T ; thread -> rows ty*4.., cols tx*2..
        float sacc[4][2] = {};
        for (int k = 0; k < DDIM; k += 4) {
            float4 a0 = *reinterpret_cast<const float4*>(&Qs[ty * 4 + 0][k]);
            float4 a1 = *reinterpret_cast<const float4*>(&Qs[ty * 4 + 1][k]);
            float4 a2 = *reinterpret_cast<const float4*>(&Qs[ty * 4 + 2][k]);
            float4 a3 = *reinterpret_cast<const float4*>(&Qs[ty * 4 + 3][k]);
            float4 b0 = *reinterpret_cast<const float4*>(&Ks[tx * 2 + 0][k]);
            float4 b1 = *reinterpret_cast<const float4*>(&Ks[tx * 2 + 1][k]);
            sacc[0][0] += a0.x*b0.x + a0.y*b0.y + a0.z*b0.z + a0.w*b0.w;
            sacc[0][1] += a0.x*b1.x + a0.y*b1.y + a0.z*b1.z + a0.w*b1.w;
            sacc[1][0] += a1.x*b0.x + a1.y*b0.y + a1.z*b0.z + a1.w*b0.w;
            sacc[1][1] += a1.x*b1.x + a1.y*b1.y + a1.z*b1.z + a1.w*b1.w;
            sacc[2][0] += a2.x*b0.x + a2.y*b0.y + a2.z*b0.z + a2.w*b0.w;
            sacc[2][1] += a2.x*b1.x + a2.y*b1.y + a2.z*b1.z + a2.w*b1.w;
            sacc[3][0] += a3.x*b0.x + a3.y*b0.y + a3.z*b0.z + a3.w*b0.w;
            sacc[3][1] += a3.x*b1.x + a3.y*b1.y + a3.z*b1.z + a3.w*b1.w;
        }
        #pragma unroll
        for (int i = 0; i < 4; ++i)
            #pragma unroll
            for (int j = 0; j < 2; ++j)
                Ss[ty * 4 + i][tx * 2 + j] = tanhf(sacc[i][j]);
        __syncthreads();

        // PV phase: acc[i][j] += Ss[row][c] * Vs[c][tx*8+j]
        for (int c = 0; c < 32; ++c) {
            float4 v0 = *reinterpret_cast<const float4*>(&Vs[c][tx * 8]);
            float4 v1 = *reinterpret_cast<const float4*>(&Vs[c][tx * 8 + 4]);
            #pragma unroll
            for (int i = 0; i < 4; ++i) {
                float sv = Ss[ty * 4 + i][c];
                acc[i][0] = fmaf(sv, v0.x, acc[i][0]);
                acc[i][1] = fmaf(sv, v0.y, acc[i][1]);
                acc[i][2] = fmaf(sv, v0.z, acc[i][2]);
                acc[i][3] = fmaf(sv, v0.w, acc[i][3]);
                acc[i][4] = fmaf(sv, v1.x, acc[i][4]);
                acc[i][5] = fmaf(sv, v1.y, acc[i][5]);
                acc[i][6] = fmaf(sv, v1.z, acc[i][6]);
                acc[i][7] = fmaf(sv, v1.w, acc[i][7]);
            }
        }
    }

    // epilogue: H = tanh(Bias + acc), partial dot with w, reduce across tx
    __syncthreads();
    const size_t bbase = ((size_t)b * L_SEQ + r0) * ADIM;
    float wv[8];
    #pragma unroll
    for (int j = 0; j < 8; ++j) wv[j] = w[tx * 8 + j];
    #pragma unroll
    for (int i = 0; i < 4; ++i) {
        int row = ty * 4 + i;
        float p = 0.f;
        #pragma unroll
        for (int j = 0; j < 8; ++j) {
            float h = tanhf(Bias[bbase + (size_t)row * ADIM + tx * 8 + j] + acc[i][j]);
            p = fmaf(h, wv[j], p);
        }
        red[row][tx] = p;
    }
    __syncthreads();
    if (tid < 64) {
        float s = 0.f;
        #pragma unroll
        for (int t = 0; t < 16; ++t) s += red[tid][t];
        logits[(size_t)b * L_SEQ + r0 + tid] = s;
    }
}

// ---------------------------------------------------------------------------
// Kernel 4: faithful masked softmax + attention-weighted row sum.
// grid (32, 2): y=0 -> v path (logits_v, mask1, f1), y=1 -> q path.
// ---------------------------------------------------------------------------
__global__ __launch_bounds__(256) void softmax_wsum(
        const float* __restrict__ lo_v, const float* __restrict__ lo_q,
        const int* __restrict__ mask1,  const int* __restrict__ mask2,
        const float* __restrict__ f1,   const float* __restrict__ f2,
        float* __restrict__ out) {
    __shared__ float att[L_SEQ];
    __shared__ float red[256];
    const int tid = threadIdx.x;
    const int b   = blockIdx.x;
    const int sel = blockIdx.y;
    const float* logits = sel ? lo_q : lo_v;
    const int*   mask   = sel ? mask2 : mask1;
    const float* f      = sel ? f2 : f1;
    float* o = out + (size_t)sel * NB * DDIM + (size_t)b * DDIM;

    float z[4], m[4];
    float lmax = -1e30f;
    #pragma unroll
    for (int i = 0; i < 4; ++i) {
        int l = i * 256 + tid;
        float lv = logits[(size_t)b * L_SEQ + l];
        m[i] = (float)mask[(size_t)b * L_SEQ + l];
        z[i] = lv * m[i];                      // vector * mask (masked -> 0)
        lmax = fmaxf(lmax, z[i]);
    }
    red[tid] = lmax; __syncthreads();
    for (int s = 128; s > 0; s >>= 1) {
        if (tid < s) red[tid] = fmaxf(red[tid], red[tid + s]);
        __syncthreads();
    }
    const float mx = red[0];
    __syncthreads();

    float p[4], lsum = 0.f;
    #pragma unroll
    for (int i = 0; i < 4; ++i) { p[i] = expf(z[i] - mx); lsum += p[i]; }
    red[tid] = lsum; __syncthreads();
    for (int s = 128; s > 0; s >>= 1) {
        if (tid < s) red[tid] += red[tid + s];
        __syncthreads();
    }
    const float Z = red[0];                    // softmax denominator (all entries)
    __syncthreads();

    float r[4], rsum = 0.f;
    #pragma unroll
    for (int i = 0; i < 4; ++i) { r[i] = (p[i] / Z) * m[i]; rsum += r[i]; }
    red[tid] = rsum; __syncthreads();
    for (int s = 128; s > 0; s >>= 1) {
        if (tid < s) red[tid] += red[tid + s];
        __syncthreads();
    }
    const float denom = red[0] + 1e-13f;       // re-mask + renormalize (EPS)
    __syncthreads();

    #pragma unroll
    for (int i = 0; i < 4; ++i) att[i * 256 + tid] = r[i] / denom;
    __syncthreads();

    // v_hat[d] = sum_l att[l] * f[b,l,d]; thread = d (coalesced over d)
    const float* fb = f + (size_t)b * L_SEQ * DDIM + tid;
    float acc = 0.f;
    for (int l = 0; l < L_SEQ; l += 4) {
        acc = fmaf(att[l + 0], fb[(size_t)(l + 0) * DDIM], acc);
        acc = fmaf(att[l + 1], fb[(size_t)(l + 1) * DDIM], acc);
        acc = fmaf(att[l + 2], fb[(size_t)(l + 2) * DDIM], acc);
        acc = fmaf(att[l + 3], fb[(size_t)(l + 3) * DDIM], acc);
    }
    o[tid] = acc;
}

// ---------------------------------------------------------------------------
extern "C" void kernel_launch(void* const* d_in, const int* in_sizes, int n_in,
                              void* d_out, int out_size, void* d_ws, size_t ws_size,
                              hipStream_t stream) {
    const float* f1   = (const float*)d_in[0];
    const float* f2   = (const float*)d_in[1];
    const int*   mask1 = (const int*)d_in[2];
    const int*   mask2 = (const int*)d_in[3];
    const float* W    = (const float*)d_in[4];
    const float* Wv   = (const float*)d_in[5];
    const float* Wq   = (const float*)d_in[6];
    const float* w_hv = (const float*)d_in[7];
    const float* w_hq = (const float*)d_in[8];
    float* out = (float*)d_out;

    // workspace layout (floats): needs ~64.3 MB
    float* ws    = (float*)d_ws;
    float* f1W   = ws;                       // [32,1024,256] = 8388608
    float* f1Wv  = f1W  + 8388608;           // [32,1024,128] = 4194304
    float* f2Wq  = f1Wv + 4194304;           // [32,1024,128] = 4194304
    float* lo_v  = f2Wq + 4194304;           // [32,1024]
    float* lo_q  = lo_v + 32768;             // [32,1024]

    const int M = NB * L_SEQ;                // 32768 (batch folds into rows)

    gemm_f32<<<dim3(DDIM / 64, M / 64), 256, 0, stream>>>(f1, W,  f1W,  M, DDIM, DDIM);
    gemm_f32<<<dim3(ADIM / 64, M / 64), 256, 0, stream>>>(f1, Wv, f1Wv, M, ADIM, DDIM);
    gemm_f32<<<dim3(ADIM / 64, M / 64), 256, 0, stream>>>(f2, Wq, f2Wq, M, ADIM, DDIM);

    // Hv path: S = tanh(f1W . f2^T), acc = S @ f2Wq, H = tanh(f1Wv + acc), logit = H.w_hv
    fused_logits<<<dim3(L_SEQ / 64, NB), 256, 0, stream>>>(f1W, f2, f2Wq, f1Wv, w_hv, lo_v);
    // Hq path: S' = tanh(f2 . f1W^T) (= C^T tile), acc = S' @ f1Wv, H = tanh(f2Wq + acc)
    fused_logits<<<dim3(L_SEQ / 64, NB), 256, 0, stream>>>(f2, f1W, f1Wv, f2Wq, w_hq, lo_q);

    softmax_wsum<<<dim3(NB, 2), 256, 0, stream>>>(lo_v, lo_q, mask1, mask2, f1, f2, out);
}

// Round 2
// 395.459 us; speedup vs baseline: 3.6966x; 3.6966x over previous
//
#include <hip/hip_runtime.h>
#include <math.h>

#define L_SEQ 1024
#define DDIM  256
#define ADIM  128
#define NB    32

typedef __attribute__((ext_vector_type(8))) short bf16x8;
typedef __attribute__((ext_vector_type(4))) float f32x4;

__device__ __forceinline__ ushort f2bf(float x) {      // fp32 -> bf16 RNE
    uint u = __builtin_bit_cast(uint, x);
    u = (u + 0x7FFFu + ((u >> 16) & 1u)) >> 16;
    return (ushort)u;
}
__device__ __forceinline__ float bf2f(ushort h) {
    uint u = ((uint)h) << 16;
    return __builtin_bit_cast(float, u);
}
__device__ __forceinline__ float tanh_fast(float x) {
    float ax = fabsf(x);
    float e  = __expf(ax * -2.0f);                     // v_exp path, hazard-safe
    float r  = (1.0f - e) * __builtin_amdgcn_rcpf(1.0f + e);
    return copysignf(r, x);
}

// ---------------------------------------------------------------------------
// fp32 -> bf16 elementwise convert (n multiple of 8)
// ---------------------------------------------------------------------------
__global__ __launch_bounds__(256) void cvt_bf16(const float* __restrict__ in,
                                                ushort* __restrict__ out, int n) {
    int i = (blockIdx.x * 256 + threadIdx.x) * 8;
    if (i >= n) return;
    float4 a = *reinterpret_cast<const float4*>(&in[i]);
    float4 b = *reinterpret_cast<const float4*>(&in[i + 4]);
    ushort4 lo = { f2bf(a.x), f2bf(a.y), f2bf(a.z), f2bf(a.w) };
    ushort4 hi = { f2bf(b.x), f2bf(b.y), f2bf(b.z), f2bf(b.w) };
    *reinterpret_cast<ushort4*>(&out[i]) = lo;
    *reinterpret_cast<ushort4*>(&out[i + 4]) = hi;
}

// ---------------------------------------------------------------------------
// fp32-compute GEMM, bf16 output: C[M,N] = bf16(A[M,K] @ B[K,N])
// ---------------------------------------------------------------------------
__global__ __launch_bounds__(256) void gemm_f32_bf16(const float* __restrict__ A,
                                                     const float* __restrict__ B,
                                                     ushort* __restrict__ C,
                                                     int M, int N, int K) {
    __shared__ float As[64][17];
    __shared__ float Bs[16][64];
    const int tid = threadIdx.x;
    const int tx = tid & 15;
    const int ty = tid >> 4;
    const int m0 = blockIdx.y * 64;
    const int n0 = blockIdx.x * 64;

    float acc[4][4] = {};
    for (int k0 = 0; k0 < K; k0 += 16) {
        {
            int row = tid >> 2;
            int kk  = (tid & 3) * 4;
            float4 v = *reinterpret_cast<const float4*>(&A[(size_t)(m0 + row) * K + k0 + kk]);
            As[row][kk + 0] = v.x; As[row][kk + 1] = v.y;
            As[row][kk + 2] = v.z; As[row][kk + 3] = v.w;
        }
        {
            int kk  = tid >> 4;
            int col = (tid & 15) * 4;
            *reinterpret_cast<float4*>(&Bs[kk][col]) =
                *reinterpret_cast<const float4*>(&B[(size_t)(k0 + kk) * N + n0 + col]);
        }
        __syncthreads();
        #pragma unroll
        for (int kk = 0; kk < 16; ++kk) {
            float a[4];
            #pragma unroll
            for (int i = 0; i < 4; ++i) a[i] = As[ty * 4 + i][kk];
            float4 bv = *reinterpret_cast<const float4*>(&Bs[kk][tx * 4]);
            float b[4] = {bv.x, bv.y, bv.z, bv.w};
            #pragma unroll
            for (int i = 0; i < 4; ++i)
                #pragma unroll
                for (int j = 0; j < 4; ++j)
                    acc[i][j] = fmaf(a[i], b[j], acc[i][j]);
        }
        __syncthreads();
    }
    #pragma unroll
    for (int i = 0; i < 4; ++i) {
        ushort4 o = { f2bf(acc[i][0]), f2bf(acc[i][1]), f2bf(acc[i][2]), f2bf(acc[i][3]) };
        *reinterpret_cast<ushort4*>(&C[(size_t)(m0 + ty * 4 + i) * N + n0 + tx * 4]) = o;
    }
}

// ---------------------------------------------------------------------------
// Fused MFMA kernel:
//   logits[b,r] = ( tanh( Bias[b,r,:] + sum_c tanh(Q[b,r,:].K[b,c,:]) * V[b,c,:] ) ) . w
// Q,K: [B,L,256] bf16   V,Bias: [B,L,128] bf16   w: [128] f32   logits: [B,L] f32
// Block: 256 thr = 4 waves, 64 Q-rows (16/wave), key chunks of 32.
// mfma_f32_16x16x32_bf16 for both S and PV. LDS 69 KB -> 2 blocks/CU.
// ---------------------------------------------------------------------------
__global__ __launch_bounds__(256) void fused_logits_mfma(
        const ushort* __restrict__ Qb, const ushort* __restrict__ Kb,
        const ushort* __restrict__ Vb, const ushort* __restrict__ Biasb,
        const float*  __restrict__ w,  float* __restrict__ logits) {
    __shared__ ushort QsU[64 * 256];   // XOR-swizzled: elem ^= (row&7)<<3
    __shared__ ushort KsU[32 * 256];   // XOR-swizzled
    __shared__ ushort VtU[128 * 56];   // V^T [a][key], stride 56 (pad)
    __shared__ ushort SsU[64 * 56];    // tanh(S) [qrow][key], stride 56

    const int tid  = threadIdx.x;
    const int lane = tid & 63;
    const int wid  = tid >> 6;
    const int wrow = wid * 16;         // wave's 16 rows within the 64-row tile
    const int l16  = lane & 15;
    const int lg   = lane >> 4;        // 0..3
    const int b    = blockIdx.y;
    const int r0   = blockIdx.x * 64;

    // ---- stage Q tile (64 x 256), once
    const size_t qbase = ((size_t)b * L_SEQ + r0) * DDIM;
    #pragma unroll
    for (int it = 0; it < 8; ++it) {
        int idx = it * 2048 + tid * 8;
        int row = idx >> 8, d0 = idx & 255;
        uint4 v = *reinterpret_cast<const uint4*>(&Qb[qbase + (size_t)row * DDIM + d0]);
        *reinterpret_cast<uint4*>(&QsU[(row * 256 + d0) ^ ((row & 7) << 3)]) = v;
    }

    f32x4 acc[8];
    #pragma unroll
    for (int i = 0; i < 8; ++i) acc[i] = (f32x4){0.f, 0.f, 0.f, 0.f};

    const int arow = wrow + l16;              // A-fragment row (QK and PV)
    const int aoff = arow * 256;
    const int aswz = (arow & 7) << 3;
    const int kswz = (l16 & 7) << 3;

    for (int c0 = 0; c0 < L_SEQ; c0 += 32) {
        __syncthreads();                      // prev-chunk consumers done
        // ---- stage K chunk (32 x 256)
        const size_t kbase = ((size_t)b * L_SEQ + c0) * DDIM;
        #pragma unroll
        for (int it = 0; it < 4; ++it) {
            int idx = it * 2048 + tid * 8;
            int row = idx >> 8, d0 = idx & 255;
            uint4 v = *reinterpret_cast<const uint4*>(&Kb[kbase + (size_t)row * DDIM + d0]);
            *reinterpret_cast<uint4*>(&KsU[(row * 256 + d0) ^ ((row & 7) << 3)]) = v;
        }
        // ---- stage V chunk (32 x 128), transposed into Vt[a][key]
        const size_t vbase = ((size_t)b * L_SEQ + c0) * ADIM;
        #pragma unroll
        for (int it = 0; it < 2; ++it) {
            int key = (tid >> 4) + it * 16;
            int a0  = (tid & 15) * 8;
            union { uint4 v4; ushort us[8]; } u;
            u.v4 = *reinterpret_cast<const uint4*>(&Vb[vbase + (size_t)key * ADIM + a0]);
            #pragma unroll
            for (int j = 0; j < 8; ++j) VtU[(a0 + j) * 56 + key] = u.us[j];
        }
        __syncthreads();                      // staging visible

        // ---- S = Q . K^T  (wave: M=16 rows, N=32 keys, K=256)
        f32x4 s0 = (f32x4){0.f, 0.f, 0.f, 0.f};
        f32x4 s1 = (f32x4){0.f, 0.f, 0.f, 0.f};
        #pragma unroll
        for (int ks = 0; ks < 8; ++ks) {
            int d = ks * 32 + lg * 8;
            bf16x8 aq = *reinterpret_cast<const bf16x8*>(&QsU[(aoff + d) ^ aswz]);
            bf16x8 b0 = *reinterpret_cast<const bf16x8*>(&KsU[(l16 * 256 + d) ^ kswz]);
            bf16x8 b1 = *reinterpret_cast<const bf16x8*>(&KsU[((16 + l16) * 256 + d) ^ kswz]);
            s0 = __builtin_amdgcn_mfma_f32_16x16x32_bf16(aq, b0, s0, 0, 0, 0);
            s1 = __builtin_amdgcn_mfma_f32_16x16x32_bf16(aq, b1, s1, 0, 0, 0);
        }
        // ---- tanh -> Ss (C-layout: row=(lg*4+r), col=l16)
        {
            int srow = wrow + lg * 4;
            #pragma unroll
            for (int r = 0; r < 4; ++r) {
                SsU[(srow + r) * 56 + l16]      = f2bf(tanh_fast(s0[r]));
                SsU[(srow + r) * 56 + 16 + l16] = f2bf(tanh_fast(s1[r]));
            }
        }
        __syncthreads();                      // Ss visible

        // ---- acc += S @ V  (M=16 rows, N=128, K=32)
        bf16x8 sa = *reinterpret_cast<const bf16x8*>(&SsU[arow * 56 + lg * 8]);
        #pragma unroll
        for (int nt = 0; nt < 8; ++nt) {
            bf16x8 vb = *reinterpret_cast<const bf16x8*>(&VtU[(nt * 16 + l16) * 56 + lg * 8]);
            acc[nt] = __builtin_amdgcn_mfma_f32_16x16x32_bf16(sa, vb, acc[nt], 0, 0, 0);
        }
    }

    // ---- epilogue: lane holds O[row=wrow+lg*4+r][col=nt*16+l16]
    float wv[8];
    #pragma unroll
    for (int nt = 0; nt < 8; ++nt) wv[nt] = w[nt * 16 + l16];
    const size_t bbase = ((size_t)b * L_SEQ + r0) * ADIM;
    #pragma unroll
    for (int r = 0; r < 4; ++r) {
        int row = wrow + lg * 4 + r;
        float p = 0.f;
        #pragma unroll
        for (int nt = 0; nt < 8; ++nt) {
            float bias = bf2f(Biasb[bbase + (size_t)row * ADIM + nt * 16 + l16]);
            p = fmaf(tanh_fast(bias + acc[nt][r]), wv[nt], p);
        }
        p += __shfl_xor(p, 1);
        p += __shfl_xor(p, 2);
        p += __shfl_xor(p, 4);
        p += __shfl_xor(p, 8);
        if (l16 == 0) logits[(size_t)b * L_SEQ + r0 + row] = p;
    }
}

// ---------------------------------------------------------------------------
// Faithful masked softmax + attention-weighted row sum (unchanged).
// ---------------------------------------------------------------------------
__global__ __launch_bounds__(256) void softmax_wsum(
        const float* __restrict__ lo_v, const float* __restrict__ lo_q,
        const int* __restrict__ mask1,  const int* __restrict__ mask2,
        const float* __restrict__ f1,   const float* __restrict__ f2,
        float* __restrict__ out) {
    __shared__ float att[L_SEQ];
    __shared__ float red[256];
    const int tid = threadIdx.x;
    const int b   = blockIdx.x;
    const int sel = blockIdx.y;
    const float* logits = sel ? lo_q : lo_v;
    const int*   mask   = sel ? mask2 : mask1;
    const float* f      = sel ? f2 : f1;
    float* o = out + (size_t)sel * NB * DDIM + (size_t)b * DDIM;

    float z[4], m[4];
    float lmax = -1e30f;
    #pragma unroll
    for (int i = 0; i < 4; ++i) {
        int l = i * 256 + tid;
        float lv = logits[(size_t)b * L_SEQ + l];
        m[i] = (float)mask[(size_t)b * L_SEQ + l];
        z[i] = lv * m[i];
        lmax = fmaxf(lmax, z[i]);
    }
    red[tid] = lmax; __syncthreads();
    for (int s = 128; s > 0; s >>= 1) {
        if (tid < s) red[tid] = fmaxf(red[tid], red[tid + s]);
        __syncthreads();
    }
    const float mx = red[0];
    __syncthreads();

    float p[4], lsum = 0.f;
    #pragma unroll
    for (int i = 0; i < 4; ++i) { p[i] = expf(z[i] - mx); lsum += p[i]; }
    red[tid] = lsum; __syncthreads();
    for (int s = 128; s > 0; s >>= 1) {
        if (tid < s) red[tid] += red[tid + s];
        __syncthreads();
    }
    const float Z = red[0];
    __syncthreads();

    float r[4], rsum = 0.f;
    #pragma unroll
    for (int i = 0; i < 4; ++i) { r[i] = (p[i] / Z) * m[i]; rsum += r[i]; }
    red[tid] = rsum; __syncthreads();
    for (int s = 128; s > 0; s >>= 1) {
        if (tid < s) red[tid] += red[tid + s];
        __syncthreads();
    }
    const float denom = red[0] + 1e-13f;
    __syncthreads();

    #pragma unroll
    for (int i = 0; i < 4; ++i) att[i * 256 + tid] = r[i] / denom;
    __syncthreads();

    const float* fb = f + (size_t)b * L_SEQ * DDIM + tid;
    float acc = 0.f;
    for (int l = 0; l < L_SEQ; l += 4) {
        acc = fmaf(att[l + 0], fb[(size_t)(l + 0) * DDIM], acc);
        acc = fmaf(att[l + 1], fb[(size_t)(l + 1) * DDIM], acc);
        acc = fmaf(att[l + 2], fb[(size_t)(l + 2) * DDIM], acc);
        acc = fmaf(att[l + 3], fb[(size_t)(l + 3) * DDIM], acc);
    }
    o[tid] = acc;
}

// ---------------------------------------------------------------------------
extern "C" void kernel_launch(void* const* d_in, const int* in_sizes, int n_in,
                              void* d_out, int out_size, void* d_ws, size_t ws_size,
                              hipStream_t stream) {
    const float* f1    = (const float*)d_in[0];
    const float* f2    = (const float*)d_in[1];
    const int*   mask1 = (const int*)d_in[2];
    const int*   mask2 = (const int*)d_in[3];
    const float* W     = (const float*)d_in[4];
    const float* Wv    = (const float*)d_in[5];
    const float* Wq    = (const float*)d_in[6];
    const float* w_hv  = (const float*)d_in[7];
    const float* w_hq  = (const float*)d_in[8];
    float* out = (float*)d_out;

    // workspace (bytes): 4 bf16 arrays + 2 logit arrays = 50.6 MB
    ushort* f1Wb  = (ushort*)d_ws;              // [32,1024,256] bf16
    ushort* f2b   = f1Wb  + 8388608;            // [32,1024,256] bf16
    ushort* f1Wvb = f2b   + 8388608;            // [32,1024,128] bf16
    ushort* f2Wqb = f1Wvb + 4194304;            // [32,1024,128] bf16
    float*  lo_v  = (float*)(f2Wqb + 4194304);  // [32,1024]
    float*  lo_q  = lo_v + 32768;               // [32,1024]

    const int M = NB * L_SEQ;                   // 32768

    cvt_bf16<<<4096, 256, 0, stream>>>(f2, f2b, 8388608);
    gemm_f32_bf16<<<dim3(4, 512), 256, 0, stream>>>(f1, W,  f1Wb,  M, DDIM, DDIM);
    gemm_f32_bf16<<<dim3(2, 512), 256, 0, stream>>>(f1, Wv, f1Wvb, M, ADIM, DDIM);
    gemm_f32_bf16<<<dim3(2, 512), 256, 0, stream>>>(f2, Wq, f2Wqb, M, ADIM, DDIM);

    // Hv: Q=f1W, K=f2, V=f2Wq, Bias=f1Wv
    fused_logits_mfma<<<dim3(16, 32), 256, 0, stream>>>(f1Wb, f2b, f2Wqb, f1Wvb, w_hv, lo_v);
    // Hq: Q=f2, K=f1W, V=f1Wv, Bias=f2Wq
    fused_logits_mfma<<<dim3(16, 32), 256, 0, stream>>>(f2b, f1Wb, f1Wvb, f2Wqb, w_hq, lo_q);

    softmax_wsum<<<dim3(NB, 2), 256, 0, stream>>>(lo_v, lo_q, mask1, mask2, f1, f2, out);
}

// Round 3
// 265.239 us; speedup vs baseline: 5.5115x; 1.4909x over previous
//
#include <hip/hip_runtime.h>
#include <math.h>

#define L_SEQ 1024
#define DDIM  256
#define ADIM  128
#define NB    32

typedef __attribute__((ext_vector_type(8))) short bf16x8;
typedef __attribute__((ext_vector_type(4))) float f32x4;

__device__ __forceinline__ ushort f2bf(float x) {      // fp32 -> bf16 RNE
    uint u = __builtin_bit_cast(uint, x);
    u = (u + 0x7FFFu + ((u >> 16) & 1u)) >> 16;
    return (ushort)u;
}
__device__ __forceinline__ float bf2f(ushort h) {
    uint u = ((uint)h) << 16;
    return __builtin_bit_cast(float, u);
}
__device__ __forceinline__ float tanh_fast(float x) {
    float ax = fabsf(x);
    float e  = __expf(ax * -2.0f);
    float r  = (1.0f - e) * __builtin_amdgcn_rcpf(1.0f + e);
    return copysignf(r, x);
}
// async global->LDS, 16B per lane; lds_dst wave-uniform, g_src per-lane
__device__ __forceinline__ void async_copy16(ushort* lds_dst, const ushort* g_src) {
    __builtin_amdgcn_global_load_lds(
        (const __attribute__((address_space(1))) unsigned int*)(g_src),
        (__attribute__((address_space(3))) unsigned int*)(lds_dst),
        16, 0, 0);
}

// ---------------------------------------------------------------------------
// fp32 -> bf16 elementwise convert (n multiple of 8)
// ---------------------------------------------------------------------------
__global__ __launch_bounds__(256) void cvt_bf16(const float* __restrict__ in,
                                                ushort* __restrict__ out, int n) {
    int i = (blockIdx.x * 256 + threadIdx.x) * 8;
    if (i >= n) return;
    float4 a = *reinterpret_cast<const float4*>(&in[i]);
    float4 b = *reinterpret_cast<const float4*>(&in[i + 4]);
    ushort4 lo = { f2bf(a.x), f2bf(a.y), f2bf(a.z), f2bf(a.w) };
    ushort4 hi = { f2bf(b.x), f2bf(b.y), f2bf(b.z), f2bf(b.w) };
    *reinterpret_cast<ushort4*>(&out[i]) = lo;
    *reinterpret_cast<ushort4*>(&out[i + 4]) = hi;
}

// ---------------------------------------------------------------------------
// fp32-compute GEMM, bf16 output: C[M,N] = bf16(A[M,K] @ B[K,N])
// ---------------------------------------------------------------------------
__global__ __launch_bounds__(256) void gemm_f32_bf16(const float* __restrict__ A,
                                                     const float* __restrict__ B,
                                                     ushort* __restrict__ C,
                                                     int M, int N, int K) {
    __shared__ float As[64][17];
    __shared__ float Bs[16][64];
    const int tid = threadIdx.x;
    const int tx = tid & 15;
    const int ty = tid >> 4;
    const int m0 = blockIdx.y * 64;
    const int n0 = blockIdx.x * 64;

    float acc[4][4] = {};
    for (int k0 = 0; k0 < K; k0 += 16) {
        {
            int row = tid >> 2;
            int kk  = (tid & 3) * 4;
            float4 v = *reinterpret_cast<const float4*>(&A[(size_t)(m0 + row) * K + k0 + kk]);
            As[row][kk + 0] = v.x; As[row][kk + 1] = v.y;
            As[row][kk + 2] = v.z; As[row][kk + 3] = v.w;
        }
        {
            int kk  = tid >> 4;
            int col = (tid & 15) * 4;
            *reinterpret_cast<float4*>(&Bs[kk][col]) =
                *reinterpret_cast<const float4*>(&B[(size_t)(k0 + kk) * N + n0 + col]);
        }
        __syncthreads();
        #pragma unroll
        for (int kk = 0; kk < 16; ++kk) {
            float a[4];
            #pragma unroll
            for (int i = 0; i < 4; ++i) a[i] = As[ty * 4 + i][kk];
            float4 bv = *reinterpret_cast<const float4*>(&Bs[kk][tx * 4]);
            float b[4] = {bv.x, bv.y, bv.z, bv.w};
            #pragma unroll
            for (int i = 0; i < 4; ++i)
                #pragma unroll
                for (int j = 0; j < 4; ++j)
                    acc[i][j] = fmaf(a[i], b[j], acc[i][j]);
        }
        __syncthreads();
    }
    #pragma unroll
    for (int i = 0; i < 4; ++i) {
        ushort4 o = { f2bf(acc[i][0]), f2bf(acc[i][1]), f2bf(acc[i][2]), f2bf(acc[i][3]) };
        *reinterpret_cast<ushort4*>(&C[(size_t)(m0 + ty * 4 + i) * N + n0 + tx * 4]) = o;
    }
}

// ---------------------------------------------------------------------------
// Fused MFMA kernel (merged both paths via blockIdx.z):
//   logits[b,r] = ( tanh( Bias[b,r,:] + sum_c tanh(Q[b,r,:].K[b,c,:]) * V[b,c,:] ) ) . w
// LDS 37 KB -> 4 blocks/CU. Q frags in registers. K via global_load_lds
// (swizzled source). V staged by coalesced column gather + b128 writes.
// ---------------------------------------------------------------------------
__global__ __launch_bounds__(256, 4) void fused_logits_mfma(
        const ushort* __restrict__ f1Wb, const ushort* __restrict__ f2b,
        const ushort* __restrict__ f1Wvb, const ushort* __restrict__ f2Wqb,
        const float* __restrict__ w_hv,  const float* __restrict__ w_hq,
        float* __restrict__ lo_v, float* __restrict__ lo_q) {
    __shared__ ushort KsU[32 * 256];   // swizzled content: Ks[row*256+d] = K[row][d ^ ((row&7)<<3)]
    __shared__ ushort VtU[128 * 56];   // V^T [a][key], stride 56
    __shared__ ushort SsU[64 * 56];    // tanh(S) [qrow][key], stride 56

    const int tid  = threadIdx.x;
    const int lane = tid & 63;
    const int wid  = tid >> 6;
    const int wrow = wid * 16;
    const int l16  = lane & 15;
    const int lg   = lane >> 4;
    const int b    = blockIdx.y;
    const int r0   = blockIdx.x * 64;
    const int z    = blockIdx.z;

    const ushort* Qb = z ? f2b   : f1Wb;
    const ushort* Kb = z ? f1Wb  : f2b;
    const ushort* Vg = z ? f1Wvb : f2Wqb;
    const ushort* Bg = z ? f2Wqb : f1Wvb;
    const float*  w  = z ? w_hq  : w_hv;
    float* logits    = z ? lo_q  : lo_v;

    // ---- Q fragments straight to registers (reused all 32 chunks)
    const int arow = wrow + l16;
    const size_t qrow_base = ((size_t)b * L_SEQ + r0 + arow) * DDIM;
    bf16x8 qf[8];
    #pragma unroll
    for (int ks = 0; ks < 8; ++ks)
        qf[ks] = *reinterpret_cast<const bf16x8*>(&Qb[qrow_base + ks * 32 + lg * 8]);

    // ---- per-lane swizzled source offsets for K global_load_lds staging
    // wave w stages rows wid*8 + it*2 + (lane>>5), 16B per lane
    int koff[4];
    #pragma unroll
    for (int it = 0; it < 4; ++it) {
        int row  = wid * 8 + it * 2 + (lane >> 5);
        int col8 = (8 * (lane & 31)) ^ ((row & 7) << 3);
        koff[it] = row * 256 + col8;
    }

    f32x4 acc[8];
    #pragma unroll
    for (int i = 0; i < 8; ++i) acc[i] = (f32x4){0.f, 0.f, 0.f, 0.f};

    const int kswz = (l16 & 7) << 3;

    for (int c0 = 0; c0 < L_SEQ; c0 += 32) {
        __syncthreads();                      // prev chunk's consumers done
        // ---- K chunk: async global->LDS, source pre-swizzled
        const ushort* gK = Kb + ((size_t)b * L_SEQ + c0) * DDIM;
        #pragma unroll
        for (int it = 0; it < 4; ++it)
            async_copy16(&KsU[(wid * 8 + it * 2) * 256], gK + koff[it]);

        // ---- V chunk: coalesced column gather -> Vt[a][key] b128 writes
        const ushort* gV = Vg + ((size_t)b * L_SEQ + c0) * ADIM;
        #pragma unroll
        for (int it = 0; it < 2; ++it) {
            int p = tid + it * 256;
            int a = p & 127, kg = p >> 7;
            const ushort* src = gV + (size_t)kg * 8 * ADIM + a;
            union { uint4 v4; ushort us[8]; } u;
            #pragma unroll
            for (int j = 0; j < 8; ++j) u.us[j] = src[(size_t)j * ADIM];
            *reinterpret_cast<uint4*>(&VtU[a * 56 + kg * 8]) = u.v4;
        }
        __syncthreads();                      // staging complete (vmcnt drained)

        // ---- S = Q . K^T  (wave: 16 rows x 32 keys, K=256)
        f32x4 s0 = (f32x4){0.f, 0.f, 0.f, 0.f};
        f32x4 s1 = (f32x4){0.f, 0.f, 0.f, 0.f};
        #pragma unroll
        for (int ks = 0; ks < 8; ++ks) {
            int d = ks * 32 + lg * 8;
            bf16x8 b0 = *reinterpret_cast<const bf16x8*>(&KsU[(l16 * 256 + d) ^ kswz]);
            bf16x8 b1 = *reinterpret_cast<const bf16x8*>(&KsU[((16 + l16) * 256 + d) ^ kswz]);
            s0 = __builtin_amdgcn_mfma_f32_16x16x32_bf16(qf[ks], b0, s0, 0, 0, 0);
            s1 = __builtin_amdgcn_mfma_f32_16x16x32_bf16(qf[ks], b1, s1, 0, 0, 0);
        }
        // ---- tanh -> Ss (C-layout: row = wrow + lg*4 + r, col = l16 / 16+l16)
        {
            int srow = wrow + lg * 4;
            #pragma unroll
            for (int r = 0; r < 4; ++r) {
                SsU[(srow + r) * 56 + l16]      = f2bf(tanh_fast(s0[r]));
                SsU[(srow + r) * 56 + 16 + l16] = f2bf(tanh_fast(s1[r]));
            }
        }
        __syncthreads();                      // Ss visible

        // ---- acc += S @ V  (16 rows x 128, K=32)
        bf16x8 sa = *reinterpret_cast<const bf16x8*>(&SsU[arow * 56 + lg * 8]);
        #pragma unroll
        for (int nt = 0; nt < 8; ++nt) {
            bf16x8 vb = *reinterpret_cast<const bf16x8*>(&VtU[(nt * 16 + l16) * 56 + lg * 8]);
            acc[nt] = __builtin_amdgcn_mfma_f32_16x16x32_bf16(sa, vb, acc[nt], 0, 0, 0);
        }
    }

    // ---- epilogue
    float wv[8];
    #pragma unroll
    for (int nt = 0; nt < 8; ++nt) wv[nt] = w[nt * 16 + l16];
    const size_t bbase = ((size_t)b * L_SEQ + r0) * ADIM;
    #pragma unroll
    for (int r = 0; r < 4; ++r) {
        int row = wrow + lg * 4 + r;
        float p = 0.f;
        #pragma unroll
        for (int nt = 0; nt < 8; ++nt) {
            float bias = bf2f(Bg[bbase + (size_t)row * ADIM + nt * 16 + l16]);
            p = fmaf(tanh_fast(bias + acc[nt][r]), wv[nt], p);
        }
        p += __shfl_xor(p, 1);
        p += __shfl_xor(p, 2);
        p += __shfl_xor(p, 4);
        p += __shfl_xor(p, 8);
        if (l16 == 0) logits[(size_t)b * L_SEQ + r0 + row] = p;
    }
}

// ---------------------------------------------------------------------------
// Faithful masked softmax + attention-weighted row sum (unchanged).
// ---------------------------------------------------------------------------
__global__ __launch_bounds__(256) void softmax_wsum(
        const float* __restrict__ lo_v, const float* __restrict__ lo_q,
        const int* __restrict__ mask1,  const int* __restrict__ mask2,
        const float* __restrict__ f1,   const float* __restrict__ f2,
        float* __restrict__ out) {
    __shared__ float att[L_SEQ];
    __shared__ float red[256];
    const int tid = threadIdx.x;
    const int b   = blockIdx.x;
    const int sel = blockIdx.y;
    const float* logits = sel ? lo_q : lo_v;
    const int*   mask   = sel ? mask2 : mask1;
    const float* f      = sel ? f2 : f1;
    float* o = out + (size_t)sel * NB * DDIM + (size_t)b * DDIM;

    float z[4], m[4];
    float lmax = -1e30f;
    #pragma unroll
    for (int i = 0; i < 4; ++i) {
        int l = i * 256 + tid;
        float lv = logits[(size_t)b * L_SEQ + l];
        m[i] = (float)mask[(size_t)b * L_SEQ + l];
        z[i] = lv * m[i];
        lmax = fmaxf(lmax, z[i]);
    }
    red[tid] = lmax; __syncthreads();
    for (int s = 128; s > 0; s >>= 1) {
        if (tid < s) red[tid] = fmaxf(red[tid], red[tid + s]);
        __syncthreads();
    }
    const float mx = red[0];
    __syncthreads();

    float p[4], lsum = 0.f;
    #pragma unroll
    for (int i = 0; i < 4; ++i) { p[i] = expf(z[i] - mx); lsum += p[i]; }
    red[tid] = lsum; __syncthreads();
    for (int s = 128; s > 0; s >>= 1) {
        if (tid < s) red[tid] += red[tid + s];
        __syncthreads();
    }
    const float Z = red[0];
    __syncthreads();

    float r[4], rsum = 0.f;
    #pragma unroll
    for (int i = 0; i < 4; ++i) { r[i] = (p[i] / Z) * m[i]; rsum += r[i]; }
    red[tid] = rsum; __syncthreads();
    for (int s = 128; s > 0; s >>= 1) {
        if (tid < s) red[tid] += red[tid + s];
        __syncthreads();
    }
    const float denom = red[0] + 1e-13f;
    __syncthreads();

    #pragma unroll
    for (int i = 0; i < 4; ++i) att[i * 256 + tid] = r[i] / denom;
    __syncthreads();

    const float* fb = f + (size_t)b * L_SEQ * DDIM + tid;
    float acc = 0.f;
    for (int l = 0; l < L_SEQ; l += 4) {
        acc = fmaf(att[l + 0], fb[(size_t)(l + 0) * DDIM], acc);
        acc = fmaf(att[l + 1], fb[(size_t)(l + 1) * DDIM], acc);
        acc = fmaf(att[l + 2], fb[(size_t)(l + 2) * DDIM], acc);
        acc = fmaf(att[l + 3], fb[(size_t)(l + 3) * DDIM], acc);
    }
    o[tid] = acc;
}

// ---------------------------------------------------------------------------
extern "C" void kernel_launch(void* const* d_in, const int* in_sizes, int n_in,
                              void* d_out, int out_size, void* d_ws, size_t ws_size,
                              hipStream_t stream) {
    const float* f1    = (const float*)d_in[0];
    const float* f2    = (const float*)d_in[1];
    const int*   mask1 = (const int*)d_in[2];
    const int*   mask2 = (const int*)d_in[3];
    const float* W     = (const float*)d_in[4];
    const float* Wv    = (const float*)d_in[5];
    const float* Wq    = (const float*)d_in[6];
    const float* w_hv  = (const float*)d_in[7];
    const float* w_hq  = (const float*)d_in[8];
    float* out = (float*)d_out;

    ushort* f1Wb  = (ushort*)d_ws;              // [32,1024,256] bf16
    ushort* f2b   = f1Wb  + 8388608;            // [32,1024,256] bf16
    ushort* f1Wvb = f2b   + 8388608;            // [32,1024,128] bf16
    ushort* f2Wqb = f1Wvb + 4194304;            // [32,1024,128] bf16
    float*  lo_v  = (float*)(f2Wqb + 4194304);  // [32,1024]
    float*  lo_q  = lo_v + 32768;               // [32,1024]

    const int M = NB * L_SEQ;                   // 32768

    cvt_bf16<<<4096, 256, 0, stream>>>(f2, f2b, 8388608);
    gemm_f32_bf16<<<dim3(4, 512), 256, 0, stream>>>(f1, W,  f1Wb,  M, DDIM, DDIM);
    gemm_f32_bf16<<<dim3(2, 512), 256, 0, stream>>>(f1, Wv, f1Wvb, M, ADIM, DDIM);
    gemm_f32_bf16<<<dim3(2, 512), 256, 0, stream>>>(f2, Wq, f2Wqb, M, ADIM, DDIM);

    fused_logits_mfma<<<dim3(16, NB, 2), 256, 0, stream>>>(
        f1Wb, f2b, f1Wvb, f2Wqb, w_hv, w_hq, lo_v, lo_q);

    softmax_wsum<<<dim3(NB, 2), 256, 0, stream>>>(lo_v, lo_q, mask1, mask2, f1, f2, out);
}

// Round 4
// 192.817 us; speedup vs baseline: 7.5816x; 1.3756x over previous
//
#include <hip/hip_runtime.h>
#include <math.h>

#define L_SEQ 1024
#define DDIM  256
#define ADIM  128
#define NB    32

typedef __attribute__((ext_vector_type(8))) short bf16x8;
typedef __attribute__((ext_vector_type(4))) float f32x4;

__device__ __forceinline__ ushort f2bf(float x) {      // fp32 -> bf16 RNE
    uint u = __builtin_bit_cast(uint, x);
    u = (u + 0x7FFFu + ((u >> 16) & 1u)) >> 16;
    return (ushort)u;
}
__device__ __forceinline__ float bf2f(ushort h) {
    uint u = ((uint)h) << 16;
    return __builtin_bit_cast(float, u);
}
__device__ __forceinline__ float tanh_fast(float x) {
    float ax = fabsf(x);
    float e  = __expf(ax * -2.0f);
    float r  = (1.0f - e) * __builtin_amdgcn_rcpf(1.0f + e);
    return copysignf(r, x);
}
// async global->LDS, 16B per lane; lds_dst wave-uniform, g_src per-lane
__device__ __forceinline__ void async_copy16(ushort* lds_dst, const ushort* g_src) {
    __builtin_amdgcn_global_load_lds(
        (const __attribute__((address_space(1))) unsigned int*)(g_src),
        (__attribute__((address_space(3))) unsigned int*)(lds_dst),
        16, 0, 0);
}

// ---------------------------------------------------------------------------
// fp32 -> bf16 elementwise convert (n multiple of 8)
// ---------------------------------------------------------------------------
__global__ __launch_bounds__(256) void cvt_bf16(const float* __restrict__ in,
                                                ushort* __restrict__ out, int n) {
    int i = (blockIdx.x * 256 + threadIdx.x) * 8;
    if (i >= n) return;
    float4 a = *reinterpret_cast<const float4*>(&in[i]);
    float4 b = *reinterpret_cast<const float4*>(&in[i + 4]);
    ushort4 lo = { f2bf(a.x), f2bf(a.y), f2bf(a.z), f2bf(a.w) };
    ushort4 hi = { f2bf(b.x), f2bf(b.y), f2bf(b.z), f2bf(b.w) };
    *reinterpret_cast<ushort4*>(&out[i]) = lo;
    *reinterpret_cast<ushort4*>(&out[i + 4]) = hi;
}

// ---------------------------------------------------------------------------
// Weight prep: w [256, N] fp32 -> WT_h/WT_l [N, 256] bf16 (transpose + split)
// grid = 256 (k rows), block = N threads
// ---------------------------------------------------------------------------
__global__ void wt_prep(const float* __restrict__ w, ushort* __restrict__ WTh,
                        ushort* __restrict__ WTl, int N) {
    int k = blockIdx.x;
    int n = threadIdx.x;
    float x = w[(size_t)k * N + n];
    ushort h = f2bf(x);
    WTh[(size_t)n * 256 + k] = h;
    WTl[(size_t)n * 256 + k] = f2bf(x - bf2f(h));
}

// ---------------------------------------------------------------------------
// Projection GEMM via MFMA + bf16 hi/lo split compensation:
//   C[M,N] = bf16( A[M,256] @ B[256,N] ),  acc = Ah*Bh + Ah*Bl + Al*Bh (fp32)
// A fp32 (split in-kernel), B pre-transposed/pre-split [N][256] bf16.
// Block: 256 thr = 4 waves; tile 64(M) x 64(N); K chunks of 32.
// ---------------------------------------------------------------------------
__global__ __launch_bounds__(256, 4) void proj_mfma(
        const float* __restrict__ A,
        const ushort* __restrict__ BTh, const ushort* __restrict__ BTl,
        ushort* __restrict__ C, int N) {
    __shared__ ushort Ash[64 * 32], Asl[64 * 32];
    __shared__ ushort Bsh[64 * 32], Bsl[64 * 32];

    const int tid  = threadIdx.x;
    const int lane = tid & 63;
    const int wid  = tid >> 6;
    const int l16  = lane & 15;
    const int lg   = lane >> 4;
    const int wrow = wid * 16;
    const int m0   = blockIdx.y * 64;
    const int n0   = blockIdx.x * 64;

    // staging coords
    const int arow = tid >> 2;            // 0..63
    const int ac0  = (tid & 3) * 8;       // 0/8/16/24 (floats within 32-chunk)
    const int bn   = wid * 16 + (lane >> 2);
    const int bk   = (lane & 3) * 8;

    f32x4 acc[4];
    #pragma unroll
    for (int i = 0; i < 4; ++i) acc[i] = (f32x4){0.f, 0.f, 0.f, 0.f};

    for (int kc = 0; kc < 8; ++kc) {
        const int k0 = kc * 32;
        __syncthreads();                  // prev chunk consumers done
        // ---- A chunk: fp32 -> hi/lo bf16 in LDS
        const float* pa = A + (size_t)(m0 + arow) * 256 + k0 + ac0;
        float4 va = *reinterpret_cast<const float4*>(pa);
        float4 vb = *reinterpret_cast<const float4*>(pa + 4);
        float xs[8] = {va.x, va.y, va.z, va.w, vb.x, vb.y, vb.z, vb.w};
        ushort h[8], l[8];
        #pragma unroll
        for (int j = 0; j < 8; ++j) {
            h[j] = f2bf(xs[j]);
            l[j] = f2bf(xs[j] - bf2f(h[j]));
        }
        *reinterpret_cast<uint4*>(&Ash[arow * 32 + ac0]) = *reinterpret_cast<uint4*>(h);
        *reinterpret_cast<uint4*>(&Asl[arow * 32 + ac0]) = *reinterpret_cast<uint4*>(l);
        // ---- B chunk: async copy from pre-split transposed weights
        async_copy16(&Bsh[wid * 16 * 32], BTh + (size_t)(n0 + bn) * 256 + k0 + bk);
        async_copy16(&Bsl[wid * 16 * 32], BTl + (size_t)(n0 + bn) * 256 + k0 + bk);
        __syncthreads();                  // staging visible

        bf16x8 ah = *reinterpret_cast<const bf16x8*>(&Ash[(wrow + l16) * 32 + lg * 8]);
        bf16x8 al = *reinterpret_cast<const bf16x8*>(&Asl[(wrow + l16) * 32 + lg * 8]);
        #pragma unroll
        for (int nf = 0; nf < 4; ++nf) {
            bf16x8 bh = *reinterpret_cast<const bf16x8*>(&Bsh[(nf * 16 + l16) * 32 + lg * 8]);
            bf16x8 bl = *reinterpret_cast<const bf16x8*>(&Bsl[(nf * 16 + l16) * 32 + lg * 8]);
            acc[nf] = __builtin_amdgcn_mfma_f32_16x16x32_bf16(ah, bh, acc[nf], 0, 0, 0);
            acc[nf] = __builtin_amdgcn_mfma_f32_16x16x32_bf16(ah, bl, acc[nf], 0, 0, 0);
            acc[nf] = __builtin_amdgcn_mfma_f32_16x16x32_bf16(al, bh, acc[nf], 0, 0, 0);
        }
    }

    #pragma unroll
    for (int nf = 0; nf < 4; ++nf)
        #pragma unroll
        for (int r = 0; r < 4; ++r)
            C[(size_t)(m0 + wrow + lg * 4 + r) * N + n0 + nf * 16 + l16] = f2bf(acc[nf][r]);
}

// ---------------------------------------------------------------------------
// Fused MFMA kernel, XCD-swizzled 1-D grid (1024 blocks):
//   xcd = w&7 owns 4 complete batches (16 row-tiles x 2 z-paths) -> K/V L2-local
// ---------------------------------------------------------------------------
__global__ __launch_bounds__(256, 4) void fused_logits_mfma(
        const ushort* __restrict__ f1Wb, const ushort* __restrict__ f2b,
        const ushort* __restrict__ f1Wvb, const ushort* __restrict__ f2Wqb,
        const float* __restrict__ w_hv,  const float* __restrict__ w_hq,
        float* __restrict__ lo_v, float* __restrict__ lo_q) {
    __shared__ ushort KsU[32 * 256];   // swizzled: Ks[row*256+d] = K[row][d ^ ((row&7)<<3)]
    __shared__ ushort VtU[128 * 56];   // V^T [a][key], stride 56
    __shared__ ushort SsU[64 * 56];    // tanh(S) [qrow][key], stride 56

    const int tid  = threadIdx.x;
    const int lane = tid & 63;
    const int wid  = tid >> 6;
    const int wrow = wid * 16;
    const int l16  = lane & 15;
    const int lg   = lane >> 4;

    // XCD-aware decode: blocks w, w+8, w+16 ... land on the same XCD (round-robin)
    const int wg   = blockIdx.x;
    const int xcd  = wg & 7;
    const int t    = wg >> 3;            // 0..127 within this XCD
    const int b    = xcd * 4 + (t >> 5); // 4 batches per XCD
    const int rem  = t & 31;
    const int z    = rem >> 4;
    const int r0   = (rem & 15) * 64;

    const ushort* Qb = z ? f2b   : f1Wb;
    const ushort* Kb = z ? f1Wb  : f2b;
    const ushort* Vg = z ? f1Wvb : f2Wqb;
    const ushort* Bg = z ? f2Wqb : f1Wvb;
    const float*  w  = z ? w_hq  : w_hv;
    float* logits    = z ? lo_q  : lo_v;

    // ---- Q fragments straight to registers (reused all 32 chunks)
    const int arow = wrow + l16;
    const size_t qrow_base = ((size_t)b * L_SEQ + r0 + arow) * DDIM;
    bf16x8 qf[8];
    #pragma unroll
    for (int ks = 0; ks < 8; ++ks)
        qf[ks] = *reinterpret_cast<const bf16x8*>(&Qb[qrow_base + ks * 32 + lg * 8]);

    // per-lane swizzled source offsets for K staging
    int koff[4];
    #pragma unroll
    for (int it = 0; it < 4; ++it) {
        int row  = wid * 8 + it * 2 + (lane >> 5);
        int col8 = (8 * (lane & 31)) ^ ((row & 7) << 3);
        koff[it] = row * 256 + col8;
    }

    f32x4 acc[8];
    #pragma unroll
    for (int i = 0; i < 8; ++i) acc[i] = (f32x4){0.f, 0.f, 0.f, 0.f};

    const int kswz = (l16 & 7) << 3;

    for (int c0 = 0; c0 < L_SEQ; c0 += 32) {
        __syncthreads();
        const ushort* gK = Kb + ((size_t)b * L_SEQ + c0) * DDIM;
        #pragma unroll
        for (int it = 0; it < 4; ++it)
            async_copy16(&KsU[(wid * 8 + it * 2) * 256], gK + koff[it]);

        const ushort* gV = Vg + ((size_t)b * L_SEQ + c0) * ADIM;
        #pragma unroll
        for (int it = 0; it < 2; ++it) {
            int p = tid + it * 256;
            int a = p & 127, kg = p >> 7;
            const ushort* src = gV + (size_t)kg * 8 * ADIM + a;
            union { uint4 v4; ushort us[8]; } u;
            #pragma unroll
            for (int j = 0; j < 8; ++j) u.us[j] = src[(size_t)j * ADIM];
            *reinterpret_cast<uint4*>(&VtU[a * 56 + kg * 8]) = u.v4;
        }
        __syncthreads();

        // ---- S = Q . K^T
        f32x4 s0 = (f32x4){0.f, 0.f, 0.f, 0.f};
        f32x4 s1 = (f32x4){0.f, 0.f, 0.f, 0.f};
        #pragma unroll
        for (int ks = 0; ks < 8; ++ks) {
            int d = ks * 32 + lg * 8;
            bf16x8 b0 = *reinterpret_cast<const bf16x8*>(&KsU[(l16 * 256 + d) ^ kswz]);
            bf16x8 b1 = *reinterpret_cast<const bf16x8*>(&KsU[((16 + l16) * 256 + d) ^ kswz]);
            s0 = __builtin_amdgcn_mfma_f32_16x16x32_bf16(qf[ks], b0, s0, 0, 0, 0);
            s1 = __builtin_amdgcn_mfma_f32_16x16x32_bf16(qf[ks], b1, s1, 0, 0, 0);
        }
        {
            int srow = wrow + lg * 4;
            #pragma unroll
            for (int r = 0; r < 4; ++r) {
                SsU[(srow + r) * 56 + l16]      = f2bf(tanh_fast(s0[r]));
                SsU[(srow + r) * 56 + 16 + l16] = f2bf(tanh_fast(s1[r]));
            }
        }
        __syncthreads();

        // ---- acc += S @ V
        bf16x8 sa = *reinterpret_cast<const bf16x8*>(&SsU[arow * 56 + lg * 8]);
        #pragma unroll
        for (int nt = 0; nt < 8; ++nt) {
            bf16x8 vb = *reinterpret_cast<const bf16x8*>(&VtU[(nt * 16 + l16) * 56 + lg * 8]);
            acc[nt] = __builtin_amdgcn_mfma_f32_16x16x32_bf16(sa, vb, acc[nt], 0, 0, 0);
        }
    }

    // ---- epilogue
    float wv[8];
    #pragma unroll
    for (int nt = 0; nt < 8; ++nt) wv[nt] = w[nt * 16 + l16];
    const size_t bbase = ((size_t)b * L_SEQ + r0) * ADIM;
    #pragma unroll
    for (int r = 0; r < 4; ++r) {
        int row = wrow + lg * 4 + r;
        float p = 0.f;
        #pragma unroll
        for (int nt = 0; nt < 8; ++nt) {
            float bias = bf2f(Bg[bbase + (size_t)row * ADIM + nt * 16 + l16]);
            p = fmaf(tanh_fast(bias + acc[nt][r]), wv[nt], p);
        }
        p += __shfl_xor(p, 1);
        p += __shfl_xor(p, 2);
        p += __shfl_xor(p, 4);
        p += __shfl_xor(p, 8);
        if (l16 == 0) logits[(size_t)b * L_SEQ + r0 + row] = p;
    }
}

// ---------------------------------------------------------------------------
// Faithful masked softmax + attention-weighted row sum (unchanged).
// ---------------------------------------------------------------------------
__global__ __launch_bounds__(256) void softmax_wsum(
        const float* __restrict__ lo_v, const float* __restrict__ lo_q,
        const int* __restrict__ mask1,  const int* __restrict__ mask2,
        const float* __restrict__ f1,   const float* __restrict__ f2,
        float* __restrict__ out) {
    __shared__ float att[L_SEQ];
    __shared__ float red[256];
    const int tid = threadIdx.x;
    const int b   = blockIdx.x;
    const int sel = blockIdx.y;
    const float* logits = sel ? lo_q : lo_v;
    const int*   mask   = sel ? mask2 : mask1;
    const float* f      = sel ? f2 : f1;
    float* o = out + (size_t)sel * NB * DDIM + (size_t)b * DDIM;

    float z[4], m[4];
    float lmax = -1e30f;
    #pragma unroll
    for (int i = 0; i < 4; ++i) {
        int l = i * 256 + tid;
        float lv = logits[(size_t)b * L_SEQ + l];
        m[i] = (float)mask[(size_t)b * L_SEQ + l];
        z[i] = lv * m[i];
        lmax = fmaxf(lmax, z[i]);
    }
    red[tid] = lmax; __syncthreads();
    for (int s = 128; s > 0; s >>= 1) {
        if (tid < s) red[tid] = fmaxf(red[tid], red[tid + s]);
        __syncthreads();
    }
    const float mx = red[0];
    __syncthreads();

    float p[4], lsum = 0.f;
    #pragma unroll
    for (int i = 0; i < 4; ++i) { p[i] = expf(z[i] - mx); lsum += p[i]; }
    red[tid] = lsum; __syncthreads();
    for (int s = 128; s > 0; s >>= 1) {
        if (tid < s) red[tid] += red[tid + s];
        __syncthreads();
    }
    const float Z = red[0];
    __syncthreads();

    float r[4], rsum = 0.f;
    #pragma unroll
    for (int i = 0; i < 4; ++i) { r[i] = (p[i] / Z) * m[i]; rsum += r[i]; }
    red[tid] = rsum; __syncthreads();
    for (int s = 128; s > 0; s >>= 1) {
        if (tid < s) red[tid] += red[tid + s];
        __syncthreads();
    }
    const float denom = red[0] + 1e-13f;
    __syncthreads();

    #pragma unroll
    for (int i = 0; i < 4; ++i) att[i * 256 + tid] = r[i] / denom;
    __syncthreads();

    const float* fb = f + (size_t)b * L_SEQ * DDIM + tid;
    float acc = 0.f;
    for (int l = 0; l < L_SEQ; l += 4) {
        acc = fmaf(att[l + 0], fb[(size_t)(l + 0) * DDIM], acc);
        acc = fmaf(att[l + 1], fb[(size_t)(l + 1) * DDIM], acc);
        acc = fmaf(att[l + 2], fb[(size_t)(l + 2) * DDIM], acc);
        acc = fmaf(att[l + 3], fb[(size_t)(l + 3) * DDIM], acc);
    }
    o[tid] = acc;
}

// ---------------------------------------------------------------------------
extern "C" void kernel_launch(void* const* d_in, const int* in_sizes, int n_in,
                              void* d_out, int out_size, void* d_ws, size_t ws_size,
                              hipStream_t stream) {
    const float* f1    = (const float*)d_in[0];
    const float* f2    = (const float*)d_in[1];
    const int*   mask1 = (const int*)d_in[2];
    const int*   mask2 = (const int*)d_in[3];
    const float* W     = (const float*)d_in[4];
    const float* Wv    = (const float*)d_in[5];
    const float* Wq    = (const float*)d_in[6];
    const float* w_hv  = (const float*)d_in[7];
    const float* w_hq  = (const float*)d_in[8];
    float* out = (float*)d_out;

    // workspace layout (ushort units) ~51 MB total
    ushort* f2b   = (ushort*)d_ws;              // [32,1024,256] bf16
    ushort* f1Wb  = f2b   + 8388608;            // [32,1024,256] bf16
    ushort* f1Wvb = f1Wb  + 8388608;            // [32,1024,128] bf16
    ushort* f2Wqb = f1Wvb + 4194304;            // [32,1024,128] bf16
    ushort* WTh   = f2Wqb + 4194304;            // [256,256]
    ushort* WTl   = WTh   + 65536;
    ushort* WvTh  = WTl   + 65536;              // [128,256]
    ushort* WvTl  = WvTh  + 32768;
    ushort* WqTh  = WvTl  + 32768;
    ushort* WqTl  = WqTh  + 32768;
    float*  lo_v  = (float*)(WqTl + 32768);     // [32,1024]
    float*  lo_q  = lo_v + 32768;               // [32,1024]

    wt_prep<<<256, 256, 0, stream>>>(W,  WTh,  WTl,  256);
    wt_prep<<<256, 128, 0, stream>>>(Wv, WvTh, WvTl, 128);
    wt_prep<<<256, 128, 0, stream>>>(Wq, WqTh, WqTl, 128);
    cvt_bf16<<<4096, 256, 0, stream>>>(f2, f2b, 8388608);

    proj_mfma<<<dim3(4, 512), 256, 0, stream>>>(f1, WTh,  WTl,  f1Wb,  256);
    proj_mfma<<<dim3(2, 512), 256, 0, stream>>>(f1, WvTh, WvTl, f1Wvb, 128);
    proj_mfma<<<dim3(2, 512), 256, 0, stream>>>(f2, WqTh, WqTl, f2Wqb, 128);

    fused_logits_mfma<<<1024, 256, 0, stream>>>(
        f1Wb, f2b, f1Wvb, f2Wqb, w_hv, w_hq, lo_v, lo_q);

    softmax_wsum<<<dim3(NB, 2), 256, 0, stream>>>(lo_v, lo_q, mask1, mask2, f1, f2, out);
}